// Round 3
// baseline (277.259 us; speedup 1.0000x reference)
//
#include <hip/hip_runtime.h>
#include <stdint.h>

#define NN 1536
#define EE 49152
#define EMB 32
#define HEADS 3
#define SLOPE 0.2f
#define CAP 72             // per-row capacity; degree ~ Poisson(32), measured max ~60 (fixed seed); P(>=72) ~ 1e-10
#define GRID 768           // 64 edges/block, 2 nodes/block, 2 rows/block

__device__ __forceinline__ float lrelu(float x){ return x >= 0.f ? x : SLOPE*x; }

// ---- runtime detection of bool-mask storage (int32 / uint8 / f32) ----
__device__ int detect_mask_layout(const unsigned char* p){
  const int* pi = (const int*)p;
  bool ok = true;
  for (int k=0;k<64 && ok;k++){ int v = pi[k]; ok = (v==0 || v==1); }
  if (ok) return 0;
  ok = true;
  for (int k=0;k<256 && ok;k++){ ok = (p[k] <= 1); }
  if (ok) return 1;
  return 2;
}
__device__ bool mask_at(const unsigned char* p, int layout, int i){
  if (layout==0) return ((const int*)p)[i] != 0;
  if (layout==1) return p[i] != 0;
  return ((const float*)p)[i] != 0.f;
}

// ---- union LDS region offsets (bytes) ----
// Phase B layout:
#define O_PAY    0                       // float4[CAP]   = 1152
#define O_SE     1152                    // float[CAP*66] = 19008
#define O_PP     20160                   // float[3*CAP]  = 864
#define O_PART   21024                   // float[8*96]   = 3072
#define O_LD     24096                   // int[CAP]      = 288
#define O_CANON  24384
#define O_SLOTI  24672
#define O_SLOTOF 24960
#define O_CDST   25248
#define UNI_SZ   25536
// Phase A layout (same region):
#define A_VEH    0                       // float[32*33] = 4224
#define A_PED    4224
#define A_UN     8448
#define A_WT     12672                   // float[96]
#define A_WN     13056                   // float[96]
#define A_F      13440                   // float[64]
#define A_EMB    13696                   // float[64]  -> ends 13952 < UNI_SZ

// LDS total ~31 KB -> 5 blocks/CU (LDS-bound); __launch_bounds__(256,3) caps VGPR so
// >=3 blocks/CU fit -> all 768 blocks co-resident -> software barrier is safe.
__global__ __launch_bounds__(256, 3) void k_fused(
    const float* __restrict__ node_f,
    const float* __restrict__ edge_attr, const float* __restrict__ edge_type,
    const float* __restrict__ W_veh, const float* __restrict__ W_ped,
    const float* __restrict__ W_ea,  const float* __restrict__ W_et,
    const float* __restrict__ W_att, const float* __restrict__ W_upd,
    const int* __restrict__ ei, const unsigned char* __restrict__ veh_mask,
    int* __restrict__ cnt, int* done,
    int* __restrict__ bucketD, float4* __restrict__ bucketF,
    float* __restrict__ nbr, float* __restrict__ nb, float* __restrict__ out)
{
  const int t = threadIdx.x;
  const int b = blockIdx.x;

  __shared__ __align__(16) char uni[UNI_SZ];
  __shared__ float sWea[64], sWet[64], sWedge[HEADS*64], sWueT[EMB*33];
  __shared__ float tarL[2][4];
  __shared__ float hden[HEADS];
  __shared__ int np_s;
  __shared__ int layout_s;

  // ---------------- Phase A: persistent weights + edge insert + node embeddings ----------------
  if (t < 64){ sWea[t] = W_ea[t]; sWet[t] = W_et[t]; }
  if (t < HEADS*64) sWedge[t] = W_att[(t>>6)*128 + EMB + (t&63)];   // W_edge
  for (int idx=t; idx<EMB*EMB; idx+=256){
    const int o = idx>>5, k = idx&31;
    sWueT[o*33+k] = W_upd[o*64 + k];     // Wu_e = W_upd[:, :32]
  }
  if (t == 0) layout_s = detect_mask_layout(veh_mask);

  float* sWvehT = (float*)(uni + A_VEH);
  float* sWpedT = (float*)(uni + A_PED);
  float* sWunT  = (float*)(uni + A_UN);
  float* sWt    = (float*)(uni + A_WT);
  float* sWn    = (float*)(uni + A_WN);
  float* sF     = (float*)(uni + A_F);
  float* sEmb   = (float*)(uni + A_EMB);

  for (int idx=t; idx<EMB*EMB; idx+=256){
    const int mm = idx>>5, kk = idx&31;
    sWvehT[mm*33+kk] = W_veh[idx];
    sWpedT[mm*33+kk] = W_ped[idx];
    sWunT[mm*33+kk]  = W_upd[mm*64 + EMB + kk];   // Wu_n = W_upd[:,32:]
  }
  if (t < HEADS*EMB){
    const int h = t>>5, c = t&31;
    sWt[t] = W_att[h*128 + c];        // W_tar
    sWn[t] = W_att[h*128 + 96 + c];   // W_nbr
  }
  if (t < 2*EMB) sF[t] = node_f[(size_t)(b*2)*EMB + t];
  __syncthreads();

  // stage 1: edge insert (t<64) ; node emb (t in [64,128))
  if (t < 64){
    const int e = b*64 + t;
    const int s = ei[e], d = ei[EE + e];
    const float2 ea = ((const float2*)edge_attr)[e];
    const float2 et = ((const float2*)edge_type)[e];
    const int idx = atomicAdd(&cnt[s], 1);
    if (idx < CAP){
      bucketD[(size_t)s*CAP + idx] = d;
      bucketF[(size_t)s*CAP + idx] = make_float4(ea.x, ea.y, et.x, et.y);
    }
  } else if (t < 128){
    const int li = (t-64) >> 5, m = t & 31;
    const int i = b*2 + li;
    const bool veh = mask_at(veh_mask, layout_s, i);
    const float* WT = veh ? sWvehT : sWpedT;
    float a = 0.f;
    #pragma unroll
    for (int k=0;k<EMB;k++) a += sF[li*EMB+k] * WT[m*33+k];
    sEmb[li*EMB+m] = lrelu(a);
  }
  __syncthreads();

  if (t >= 64 && t < 128){
    const int li = (t-64) >> 5, m = t & 31;
    const int i = b*2 + li;
    float bb = 0.f;
    #pragma unroll
    for (int k=0;k<EMB;k++) bb += sEmb[li*EMB+k] * sWunT[m*33+k];
    nb[(size_t)i*EMB + m] = bb;
    if (m < 3){
      float v = 0.f;
      #pragma unroll
      for (int k=0;k<EMB;k++) v += sEmb[li*EMB+k] * sWt[m*EMB+k];
      tarL[li][m] = v;                      // consumed only by this block's rows
    } else if (m < 6){
      const int h = m-3;
      float v = 0.f;
      #pragma unroll
      for (int k=0;k<EMB;k++) v += sEmb[li*EMB+k] * sWn[h*EMB+k];
      nbr[i*4+h] = v;
    }
  }

  // ---------------- software grid barrier (device-scope; graph-capture-safe) ----------------
  __threadfence();            // release this thread's phase-A stores
  __syncthreads();            // all block threads' fences precede the arrival
  if (t == 0){
    atomicAdd(done, 1);
    int spins = 0;
    while (atomicAdd(done, 0) < GRID){     // device-scope RMW poll (no stale cache)
      __builtin_amdgcn_s_sleep(8);
      if (++spins > 50000000) break;       // hang-breaker: fail loud, not hung
    }
  }
  __syncthreads();
  __threadfence();            // acquire side

  // ---------------- Phase B: two rows per block ----------------
  int*    ld      = (int*)   (uni + O_LD);
  int*    canon   = (int*)   (uni + O_CANON);
  int*    slotidx = (int*)   (uni + O_SLOTI);
  int*    slotof  = (int*)   (uni + O_SLOTOF);
  int*    cdst    = (int*)   (uni + O_CDST);
  float4* pay     = (float4*)(uni + O_PAY);
  float*  sE      = (float*) (uni + O_SE);
  float*  pp      = (float*) (uni + O_PP);
  float*  partial = (float*) (uni + O_PART);

  for (int rr=0; rr<2; rr++){
    const int r = b*2 + rr;
    __syncthreads();                       // LDS reuse fence (prev row readers done)
    if (t == 0) np_s = 0;

    const int K = min(cnt[r], CAP);

    if (K == 0){
      // all scores -10000 -> uniform attention over all nodes (lazy fallback; ~never taken)
      float* fb = (float*)(uni + O_PP);    // reuse pp region
      if (t < EMB) fb[t] = 0.f;
      __syncthreads();
      for (int idx=t; idx<NN*EMB; idx+=256) atomicAdd(&fb[idx&31], lrelu(nb[idx]));
      __syncthreads();
      if (t < 96) out[(size_t)r*96 + t] = fb[t&31] * (1.0f/NN);
      continue;
    }

    for (int i=t; i<K; i+=256){
      ld[i]  = bucketD[(size_t)r*CAP + i];
      pay[i] = bucketF[(size_t)r*CAP + i];
      canon[i] = i;
    }
    __syncthreads();

    // dedup: canon[i] = min j with ld[j]==ld[i] (all-parallel pair sweep)
    for (int p=t; p<K*K; p+=256){
      const int i = p / K, j = p - i*K;
      if (j < i && ld[i] == ld[j]) atomicMin(&canon[i], j);
    }
    __syncthreads();
    for (int i=t; i<K; i+=256){
      if (canon[i] == i){
        const int s2 = atomicAdd(&np_s, 1);
        slotidx[i] = s2;
        cdst[s2]   = ld[i];
      }
    }
    __syncthreads();
    const int Kc = np_s;
    const bool nodup = (Kc == K);     // block-uniform

    for (int i=t; i<K; i+=256) slotof[i] = slotidx[canon[i]];
    if (!nodup){
      for (int idx=t; idx<Kc*66; idx+=256) sE[idx] = 0.f;
    }
    __syncthreads();

    // per-entry 64-dim edge embedding -> per-slot sum (linear downstream)
    for (int idx=t; idx<K*EMB; idx+=256){
      const int q = idx>>5, m = idx&31;
      const float4 p4 = pay[q];
      const float ea_ = lrelu(p4.x*sWea[2*m] + p4.y*sWea[2*m+1]);
      const float et_ = lrelu(p4.z*sWet[2*m] + p4.w*sWet[2*m+1]);
      const int sl = slotof[q];
      if (nodup){
        sE[sl*66 + m]      = ea_;
        sE[sl*66 + 33 + m] = et_;
      } else {
        atomicAdd(&sE[sl*66 + m],      ea_);
        atomicAdd(&sE[sl*66 + 33 + m], et_);
      }
    }
    __syncthreads();

    // softmax: head h = wave h; lane q; shfl reductions
    if (t < 192){
      const int h = t >> 6, lane = t & 63;
      const float th = tarL[rr][h];
      float mx = -1e30f;
      for (int q0=0; q0<Kc; q0+=64){
        const int q = q0 + lane;
        if (q < Kc){
          float sev = 0.f;
          #pragma unroll
          for (int k=0;k<EMB;k++)
            sev += sWedge[h*64+k]*sE[q*66+k] + sWedge[h*64+EMB+k]*sE[q*66+33+k];
          const float s = lrelu(th + sev + nbr[cdst[q]*4+h]);
          pp[h*CAP+q] = s;
          mx = fmaxf(mx, s);
        }
      }
      #pragma unroll
      for (int d=32; d; d>>=1) mx = fmaxf(mx, __shfl_xor(mx, d, 64));
      float den = 0.f;
      for (int q0=0; q0<Kc; q0+=64){
        const int q = q0 + lane;
        if (q < Kc){
          const float p = __expf(pp[h*CAP+q] - mx);
          pp[h*CAP+q] = p;
          den += p;
        }
      }
      #pragma unroll
      for (int d=32; d; d>>=1) den += __shfl_xor(den, d, 64);
      if (lane == 0) hden[h] = den;
    }
    __syncthreads();

    // output: 8 q-groups x 32 o-lanes; eau recomputed from sE x sWueT
    {
      const int g = t >> 5, o = t & 31;
      float a0=0.f, a1=0.f, a2=0.f;
      for (int q=g; q<Kc; q+=8){
        float ev = 0.f;
        #pragma unroll
        for (int k=0;k<EMB;k++) ev += sWueT[o*33+k] * sE[q*66+k];
        const float u = lrelu(ev + nb[(size_t)cdst[q]*EMB + o]);
        a0 += pp[0*CAP+q]*u;
        a1 += pp[1*CAP+q]*u;
        a2 += pp[2*CAP+q]*u;
      }
      partial[g*96 +      o] = a0;
      partial[g*96 + 32 + o] = a1;
      partial[g*96 + 64 + o] = a2;
    }
    __syncthreads();
    if (t < 96){
      float s = 0.f;
      #pragma unroll
      for (int g=0; g<8; g++) s += partial[g*96 + t];
      out[(size_t)r*96 + t] = s / hden[t>>5];
    }
  }
}

extern "C" void kernel_launch(void* const* d_in, const int* in_sizes, int n_in,
                              void* d_out, int out_size, void* d_ws, size_t ws_size,
                              hipStream_t stream)
{
  (void)in_sizes; (void)n_in; (void)out_size; (void)ws_size;
  const float* node_f    = (const float*)d_in[0];
  const float* edge_attr = (const float*)d_in[1];
  const float* edge_type = (const float*)d_in[2];
  const float* W_veh     = (const float*)d_in[3];
  const float* W_ped     = (const float*)d_in[4];
  const float* W_ea      = (const float*)d_in[5];
  const float* W_et      = (const float*)d_in[6];
  const float* W_att     = (const float*)d_in[7];
  const float* W_upd     = (const float*)d_in[8];
  const int*   ei        = (const int*)d_in[9];
  const unsigned char* veh_mask = (const unsigned char*)d_in[10];
  float* out = (float*)d_out;

  char* ws = (char*)d_ws;
  const size_t oCnt  = 0;                            // NN ints
  const size_t oDone = (size_t)NN*4;                 // 1 int (barrier counter)
  const size_t oBktF = oDone + 16;                   // NN*CAP float4 (6160 % 16 == 0)
  const size_t oBktD = oBktF + (size_t)NN*CAP*16;    // NN*CAP ints
  const size_t oNbr  = oBktD + (size_t)NN*CAP*4;     // NN*4 floats
  const size_t oNb   = oNbr  + (size_t)NN*4*4;       // NN*32 floats

  int*    cnt     = (int*)   (ws + oCnt);
  int*    done    = (int*)   (ws + oDone);
  float4* bucketF = (float4*)(ws + oBktF);
  int*    bucketD = (int*)   (ws + oBktD);
  float*  nbr     = (float*) (ws + oNbr);
  float*  nb      = (float*) (ws + oNb);

  hipMemsetAsync(ws, 0, oBktF, stream);   // cnt + done = 0 (6.2 KB only)

  k_fused<<<GRID, 256, 0, stream>>>(node_f, edge_attr, edge_type,
                                    W_veh, W_ped, W_ea, W_et, W_att, W_upd,
                                    ei, veh_mask, cnt, done, bucketD, bucketF,
                                    nbr, nb, out);
}

// Round 4
// 269.828 us; speedup vs baseline: 1.0275x; 1.0275x over previous
//
#include <hip/hip_runtime.h>
#include <stdint.h>

#define NN 1536
#define EE 49152
#define EMB 32
#define HEADS 3
#define SLOPE 0.2f
#define CAP 72             // per-row capacity; degree ~ Poisson(32), measured max ~60 (fixed seed); P(>=72) ~ 1e-10
#define GRID 768           // 64 edges/block, 2 nodes/block, 2 rows/block

__device__ __forceinline__ float lrelu(float x){ return x >= 0.f ? x : SLOPE*x; }

// ---- runtime detection of bool-mask storage (int32 / uint8 / f32) ----
__device__ int detect_mask_layout(const unsigned char* p){
  const int* pi = (const int*)p;
  bool ok = true;
  for (int k=0;k<64 && ok;k++){ int v = pi[k]; ok = (v==0 || v==1); }
  if (ok) return 0;
  ok = true;
  for (int k=0;k<256 && ok;k++){ ok = (p[k] <= 1); }
  if (ok) return 1;
  return 2;
}
__device__ bool mask_at(const unsigned char* p, int layout, int i){
  if (layout==0) return ((const int*)p)[i] != 0;
  if (layout==1) return p[i] != 0;
  return ((const float*)p)[i] != 0.f;
}

// ---- union LDS region offsets (bytes) ----
// Phase B layout:
#define O_PAY    0                       // float4[CAP]   = 1152
#define O_SE     1152                    // float[CAP*66] = 19008
#define O_PP     20160                   // float[3*CAP]  = 864
#define O_PART   21024                   // float[8*96]   = 3072
#define O_LD     24096                   // int[CAP]      = 288
#define O_CANON  24384
#define O_SLOTI  24672
#define O_SLOTOF 24960
#define O_CDST   25248
#define UNI_SZ   25536
// Phase A layout (same region):
#define A_VEH    0                       // float[32*33] = 4224
#define A_PED    4224
#define A_UN     8448
#define A_WT     12672                   // float[96]
#define A_WN     13056                   // float[96]
#define A_F      13440                   // float[64]
#define A_EMB    13696                   // float[64]  -> ends 13952 < UNI_SZ

// LDS total ~31 KB -> 5 blocks/CU (LDS-bound); __launch_bounds__(256,3) caps VGPR so
// >=3 blocks/CU fit -> all 768 blocks co-resident -> software barrier is safe.
__global__ __launch_bounds__(256, 3) void k_fused(
    const float* __restrict__ node_f,
    const float* __restrict__ edge_attr, const float* __restrict__ edge_type,
    const float* __restrict__ W_veh, const float* __restrict__ W_ped,
    const float* __restrict__ W_ea,  const float* __restrict__ W_et,
    const float* __restrict__ W_att, const float* __restrict__ W_upd,
    const int* __restrict__ ei, const unsigned char* __restrict__ veh_mask,
    int* __restrict__ cnt, int* done,
    int* __restrict__ bucketD, float4* __restrict__ bucketF,
    float* __restrict__ nbr, float* __restrict__ nb, float* __restrict__ out)
{
  const int t = threadIdx.x;
  const int b = blockIdx.x;

  __shared__ __align__(16) char uni[UNI_SZ];
  __shared__ float sWea[64], sWet[64], sWedge[HEADS*64], sWueT[EMB*33];
  __shared__ float tarL[2][4];
  __shared__ float hden[HEADS];
  __shared__ int np_s;
  __shared__ int layout_s;

  // ---------------- Phase A: persistent weights + edge insert + node embeddings ----------------
  if (t < 64){ sWea[t] = W_ea[t]; sWet[t] = W_et[t]; }
  if (t < HEADS*64) sWedge[t] = W_att[(t>>6)*128 + EMB + (t&63)];   // W_edge
  for (int idx=t; idx<EMB*EMB; idx+=256){
    const int o = idx>>5, k = idx&31;
    sWueT[o*33+k] = W_upd[o*64 + k];     // Wu_e = W_upd[:, :32]
  }
  if (t == 0) layout_s = detect_mask_layout(veh_mask);

  float* sWvehT = (float*)(uni + A_VEH);
  float* sWpedT = (float*)(uni + A_PED);
  float* sWunT  = (float*)(uni + A_UN);
  float* sWt    = (float*)(uni + A_WT);
  float* sWn    = (float*)(uni + A_WN);
  float* sF     = (float*)(uni + A_F);
  float* sEmb   = (float*)(uni + A_EMB);

  for (int idx=t; idx<EMB*EMB; idx+=256){
    const int mm = idx>>5, kk = idx&31;
    sWvehT[mm*33+kk] = W_veh[idx];
    sWpedT[mm*33+kk] = W_ped[idx];
    sWunT[mm*33+kk]  = W_upd[mm*64 + EMB + kk];   // Wu_n = W_upd[:,32:]
  }
  if (t < HEADS*EMB){
    const int h = t>>5, c = t&31;
    sWt[t] = W_att[h*128 + c];        // W_tar
    sWn[t] = W_att[h*128 + 96 + c];   // W_nbr
  }
  if (t < 2*EMB) sF[t] = node_f[(size_t)(b*2)*EMB + t];
  __syncthreads();

  // stage 1: edge insert (t<64) ; node emb (t in [64,128))
  if (t < 64){
    const int e = b*64 + t;
    const int s = ei[e], d = ei[EE + e];
    const float2 ea = ((const float2*)edge_attr)[e];
    const float2 et = ((const float2*)edge_type)[e];
    const int idx = atomicAdd(&cnt[s], 1);
    if (idx < CAP){
      bucketD[(size_t)s*CAP + idx] = d;
      bucketF[(size_t)s*CAP + idx] = make_float4(ea.x, ea.y, et.x, et.y);
    }
  } else if (t < 128){
    const int li = (t-64) >> 5, m = t & 31;
    const int i = b*2 + li;
    const bool veh = mask_at(veh_mask, layout_s, i);
    const float* WT = veh ? sWvehT : sWpedT;
    float a = 0.f;
    #pragma unroll
    for (int k=0;k<EMB;k++) a += sF[li*EMB+k] * WT[m*33+k];
    sEmb[li*EMB+m] = lrelu(a);
  }
  __syncthreads();

  if (t >= 64 && t < 128){
    const int li = (t-64) >> 5, m = t & 31;
    const int i = b*2 + li;
    float bb = 0.f;
    #pragma unroll
    for (int k=0;k<EMB;k++) bb += sEmb[li*EMB+k] * sWunT[m*33+k];
    nb[(size_t)i*EMB + m] = bb;
    if (m < 3){
      float v = 0.f;
      #pragma unroll
      for (int k=0;k<EMB;k++) v += sEmb[li*EMB+k] * sWt[m*EMB+k];
      tarL[li][m] = v;                      // consumed only by this block's rows
    } else if (m < 6){
      const int h = m-3;
      float v = 0.f;
      #pragma unroll
      for (int k=0;k<EMB;k++) v += sEmb[li*EMB+k] * sWn[h*EMB+k];
      nbr[i*4+h] = v;
    }
  }

  // ---------------- software grid barrier (graph-capture-safe) ----------------
  // Arrival: ONE device-scope RMW per block. Poll: device-scope atomic LOAD
  // (shared line, concurrently servable — no RMW ownership ping-pong, which
  // collapsed round 3 to 209us) + s_sleep backoff.
  __threadfence();            // release this thread's phase-A stores
  __syncthreads();            // all block threads' fences precede the arrival
  if (t == 0){
    __hip_atomic_fetch_add(done, 1, __ATOMIC_ACQ_REL, __HIP_MEMORY_SCOPE_AGENT);
    int spins = 0;
    while (__hip_atomic_load(done, __ATOMIC_ACQUIRE, __HIP_MEMORY_SCOPE_AGENT) < GRID){
      __builtin_amdgcn_s_sleep(16);
      if (++spins > 300000) break;         // hang-breaker: fail loud, not hung
    }
  }
  __syncthreads();
  __threadfence();            // acquire side

  // ---------------- Phase B: two rows per block ----------------
  int*    ld      = (int*)   (uni + O_LD);
  int*    canon   = (int*)   (uni + O_CANON);
  int*    slotidx = (int*)   (uni + O_SLOTI);
  int*    slotof  = (int*)   (uni + O_SLOTOF);
  int*    cdst    = (int*)   (uni + O_CDST);
  float4* pay     = (float4*)(uni + O_PAY);
  float*  sE      = (float*) (uni + O_SE);
  float*  pp      = (float*) (uni + O_PP);
  float*  partial = (float*) (uni + O_PART);

  for (int rr=0; rr<2; rr++){
    const int r = b*2 + rr;
    __syncthreads();                       // LDS reuse fence (prev row readers done)
    if (t == 0) np_s = 0;

    const int K = min(cnt[r], CAP);

    if (K == 0){
      // all scores -10000 -> uniform attention over all nodes (lazy fallback; ~never taken)
      float* fb = (float*)(uni + O_PP);    // reuse pp region
      if (t < EMB) fb[t] = 0.f;
      __syncthreads();
      for (int idx=t; idx<NN*EMB; idx+=256) atomicAdd(&fb[idx&31], lrelu(nb[idx]));
      __syncthreads();
      if (t < 96) out[(size_t)r*96 + t] = fb[t&31] * (1.0f/NN);
      continue;
    }

    for (int i=t; i<K; i+=256){
      ld[i]  = bucketD[(size_t)r*CAP + i];
      pay[i] = bucketF[(size_t)r*CAP + i];
      canon[i] = i;
    }
    __syncthreads();

    // dedup: canon[i] = min j with ld[j]==ld[i] (all-parallel pair sweep)
    for (int p=t; p<K*K; p+=256){
      const int i = p / K, j = p - i*K;
      if (j < i && ld[i] == ld[j]) atomicMin(&canon[i], j);
    }
    __syncthreads();
    for (int i=t; i<K; i+=256){
      if (canon[i] == i){
        const int s2 = atomicAdd(&np_s, 1);
        slotidx[i] = s2;
        cdst[s2]   = ld[i];
      }
    }
    __syncthreads();
    const int Kc = np_s;
    const bool nodup = (Kc == K);     // block-uniform

    for (int i=t; i<K; i+=256) slotof[i] = slotidx[canon[i]];
    if (!nodup){
      for (int idx=t; idx<Kc*66; idx+=256) sE[idx] = 0.f;
    }
    __syncthreads();

    // per-entry 64-dim edge embedding -> per-slot sum (linear downstream)
    for (int idx=t; idx<K*EMB; idx+=256){
      const int q = idx>>5, m = idx&31;
      const float4 p4 = pay[q];
      const float ea_ = lrelu(p4.x*sWea[2*m] + p4.y*sWea[2*m+1]);
      const float et_ = lrelu(p4.z*sWet[2*m] + p4.w*sWet[2*m+1]);
      const int sl = slotof[q];
      if (nodup){
        sE[sl*66 + m]      = ea_;
        sE[sl*66 + 33 + m] = et_;
      } else {
        atomicAdd(&sE[sl*66 + m],      ea_);
        atomicAdd(&sE[sl*66 + 33 + m], et_);
      }
    }
    __syncthreads();

    // softmax: head h = wave h; lane q; shfl reductions
    if (t < 192){
      const int h = t >> 6, lane = t & 63;
      const float th = tarL[rr][h];
      float mx = -1e30f;
      for (int q0=0; q0<Kc; q0+=64){
        const int q = q0 + lane;
        if (q < Kc){
          float sev = 0.f;
          #pragma unroll
          for (int k=0;k<EMB;k++)
            sev += sWedge[h*64+k]*sE[q*66+k] + sWedge[h*64+EMB+k]*sE[q*66+33+k];
          const float s = lrelu(th + sev + nbr[cdst[q]*4+h]);
          pp[h*CAP+q] = s;
          mx = fmaxf(mx, s);
        }
      }
      #pragma unroll
      for (int d=32; d; d>>=1) mx = fmaxf(mx, __shfl_xor(mx, d, 64));
      float den = 0.f;
      for (int q0=0; q0<Kc; q0+=64){
        const int q = q0 + lane;
        if (q < Kc){
          const float p = __expf(pp[h*CAP+q] - mx);
          pp[h*CAP+q] = p;
          den += p;
        }
      }
      #pragma unroll
      for (int d=32; d; d>>=1) den += __shfl_xor(den, d, 64);
      if (lane == 0) hden[h] = den;
    }
    __syncthreads();

    // output: 8 q-groups x 32 o-lanes; eau recomputed from sE x sWueT
    {
      const int g = t >> 5, o = t & 31;
      float a0=0.f, a1=0.f, a2=0.f;
      for (int q=g; q<Kc; q+=8){
        float ev = 0.f;
        #pragma unroll
        for (int k=0;k<EMB;k++) ev += sWueT[o*33+k] * sE[q*66+k];
        const float u = lrelu(ev + nb[(size_t)cdst[q]*EMB + o]);
        a0 += pp[0*CAP+q]*u;
        a1 += pp[1*CAP+q]*u;
        a2 += pp[2*CAP+q]*u;
      }
      partial[g*96 +      o] = a0;
      partial[g*96 + 32 + o] = a1;
      partial[g*96 + 64 + o] = a2;
    }
    __syncthreads();
    if (t < 96){
      float s = 0.f;
      #pragma unroll
      for (int g=0; g<8; g++) s += partial[g*96 + t];
      out[(size_t)r*96 + t] = s / hden[t>>5];
    }
  }
}

extern "C" void kernel_launch(void* const* d_in, const int* in_sizes, int n_in,
                              void* d_out, int out_size, void* d_ws, size_t ws_size,
                              hipStream_t stream)
{
  (void)in_sizes; (void)n_in; (void)out_size; (void)ws_size;
  const float* node_f    = (const float*)d_in[0];
  const float* edge_attr = (const float*)d_in[1];
  const float* edge_type = (const float*)d_in[2];
  const float* W_veh     = (const float*)d_in[3];
  const float* W_ped     = (const float*)d_in[4];
  const float* W_ea      = (const float*)d_in[5];
  const float* W_et      = (const float*)d_in[6];
  const float* W_att     = (const float*)d_in[7];
  const float* W_upd     = (const float*)d_in[8];
  const int*   ei        = (const int*)d_in[9];
  const unsigned char* veh_mask = (const unsigned char*)d_in[10];
  float* out = (float*)d_out;

  char* ws = (char*)d_ws;
  const size_t oCnt  = 0;                            // NN ints
  const size_t oDone = (size_t)NN*4;                 // 1 int (barrier counter)
  const size_t oBktF = oDone + 16;                   // NN*CAP float4 (6160 % 16 == 0)
  const size_t oBktD = oBktF + (size_t)NN*CAP*16;    // NN*CAP ints
  const size_t oNbr  = oBktD + (size_t)NN*CAP*4;     // NN*4 floats
  const size_t oNb   = oNbr  + (size_t)NN*4*4;       // NN*32 floats

  int*    cnt     = (int*)   (ws + oCnt);
  int*    done    = (int*)   (ws + oDone);
  float4* bucketF = (float4*)(ws + oBktF);
  int*    bucketD = (int*)   (ws + oBktD);
  float*  nbr     = (float*) (ws + oNbr);
  float*  nb      = (float*) (ws + oNb);

  hipMemsetAsync(ws, 0, oBktF, stream);   // cnt + done = 0 (6.2 KB only)

  k_fused<<<GRID, 256, 0, stream>>>(node_f, edge_attr, edge_type,
                                    W_veh, W_ped, W_ea, W_et, W_att, W_upd,
                                    ei, veh_mask, cnt, done, bucketD, bucketF,
                                    nbr, nb, out);
}

// Round 5
// 120.347 us; speedup vs baseline: 2.3038x; 2.2421x over previous
//
#include <hip/hip_runtime.h>
#include <stdint.h>

#define NN 1536
#define EE 49152
#define EMB 32
#define HEADS 3
#define SLOPE 0.2f
#define CAP 72             // per-row capacity; degree ~ Poisson(32), measured max ~60; CAP=72 proven by passing runs
#define SES 67             // sE row stride (67 mod 32 = 3, coprime -> conflict-free softmax reads)
#define EBLK (EE/256)      // 192 edge blocks
#define NBLK (NN/8)        // 192 node blocks

__device__ __forceinline__ float lrelu(float x){ return x >= 0.f ? x : SLOPE*x; }

// ---- runtime detection of bool-mask storage (int32 / uint8 / f32) ----
__device__ int detect_mask_layout(const unsigned char* p){
  const int* pi = (const int*)p;
  bool ok = true;
  for (int k=0;k<64 && ok;k++){ int v = pi[k]; ok = (v==0 || v==1); }
  if (ok) return 0;
  ok = true;
  for (int k=0;k<256 && ok;k++){ ok = (p[k] <= 1); }
  if (ok) return 1;
  return 2;
}
__device__ bool mask_at(const unsigned char* p, int layout, int i){
  if (layout==0) return ((const int*)p)[i] != 0;
  if (layout==1) return p[i] != 0;
  return ((const float*)p)[i] != 0.f;
}

// ---- K1: blocks [0,192): pure bucket insert (1 thread/edge, payload = dst + 4 raw attrs).
//          blocks [192, 384): node embeddings. ----
__global__ __launch_bounds__(256) void k_prep(
    const float* __restrict__ node_f,
    const float* __restrict__ edge_attr, const float* __restrict__ edge_type,
    const float* __restrict__ W_veh, const float* __restrict__ W_ped,
    const float* __restrict__ W_att, const float* __restrict__ W_upd,
    const int* __restrict__ ei, const unsigned char* __restrict__ veh_mask,
    int* __restrict__ cnt, int* __restrict__ bucketD, float4* __restrict__ bucketF,
    float* __restrict__ tar, float* __restrict__ nbr, float* __restrict__ nb)
{
  const int t = threadIdx.x;
  const int b = blockIdx.x;

  if (b < EBLK){
    const int e = b*256 + t;
    const int s = ei[e], d = ei[EE + e];
    const float2 ea = ((const float2*)edge_attr)[e];
    const float2 et = ((const float2*)edge_type)[e];
    const int idx = atomicAdd(&cnt[s], 1);
    if (idx < CAP){
      bucketD[(size_t)s*CAP + idx] = d;
      bucketF[(size_t)s*CAP + idx] = make_float4(ea.x, ea.y, et.x, et.y);
    }
    return;
  }

  // -------- node path: 8 nodes/block, 32 threads/node --------
  __shared__ float sWvehT[EMB*33], sWpedT[EMB*33], sWunT[EMB*33];
  __shared__ float sWt[HEADS*EMB], sWn[HEADS*EMB];
  __shared__ float sF[8*EMB], sEmb[8*EMB];
  __shared__ int layout_s;
  const int i0 = (b - EBLK)*8;
  if (t == 0) layout_s = detect_mask_layout(veh_mask);
  for (int idx=t; idx<EMB*EMB; idx+=256){
    const int mm = idx>>5, kk = idx&31;
    sWvehT[mm*33+kk] = W_veh[idx];
    sWpedT[mm*33+kk] = W_ped[idx];
    sWunT[mm*33+kk]  = W_upd[mm*64 + EMB + kk];   // Wu_n = W_upd[:,32:]
  }
  if (t < HEADS*EMB){
    const int h = t>>5, c = t&31;
    sWt[t] = W_att[h*128 + c];        // W_tar
    sWn[t] = W_att[h*128 + 96 + c];   // W_nbr
  }
  sF[t] = node_f[(size_t)i0*EMB + t];
  __syncthreads();

  const int li = t >> 5, m = t & 31;
  const int i = i0 + li;
  const bool veh = mask_at(veh_mask, layout_s, i);
  const float* WT = veh ? sWvehT : sWpedT;
  float a = 0.f;
  #pragma unroll
  for (int k=0;k<EMB;k++) a += sF[li*EMB+k] * WT[m*33+k];
  sEmb[li*EMB+m] = lrelu(a);
  __syncthreads();

  float bb = 0.f;
  #pragma unroll
  for (int k=0;k<EMB;k++) bb += sEmb[li*EMB+k] * sWunT[m*33+k];
  nb[(size_t)i*EMB + m] = bb;
  if (m < 3){
    float v = 0.f;
    #pragma unroll
    for (int k=0;k<EMB;k++) v += sEmb[li*EMB+k] * sWt[m*EMB+k];
    tar[i*4+m] = v;
  } else if (m < 6){
    const int h = m-3;
    float v = 0.f;
    #pragma unroll
    for (int k=0;k<EMB;k++) v += sEmb[li*EMB+k] * sWn[h*EMB+k];
    nbr[i*4+h] = v;
  }
}

// ---- K2: one block per src row. LDS 25.6 KB -> 6 blocks/CU -> all 1536 rows
//          resident in ONE wave (no dispatch tail). Fast-path dedup: 5 barriers/row. ----
__global__ __launch_bounds__(256, 6) void k_rows(
    const int* __restrict__ cnt, const int* __restrict__ bucketD,
    const float4* __restrict__ bucketF,
    const float* __restrict__ W_ea, const float* __restrict__ W_et,
    const float* __restrict__ W_att, const float* __restrict__ W_upd,
    const float* __restrict__ tar, const float* __restrict__ nbr,
    const float* __restrict__ nb, float* __restrict__ out)
{
  const int r = blockIdx.x;
  const int t = threadIdx.x;

  __shared__ int   ld[CAP], canon[CAP], slotidx[CAP], slotof[CAP], cdst[CAP];
  __shared__ float4 pay[CAP];
  __shared__ float sE[CAP*SES];          // per-slot [emb_ea(32) | pad | emb_et(32) | pad2]
  __shared__ float sWea[64], sWet[64], sWedge[HEADS*64];
  __shared__ float pp[HEADS*CAP];
  __shared__ float partial[4*96];
  __shared__ float hden[HEADS];
  __shared__ int np_s, hasdup_s;

  if (t < 64){ sWea[t] = W_ea[t]; sWet[t] = W_et[t]; }
  if (t < HEADS*64) sWedge[t] = W_att[(t>>6)*128 + EMB + (t&63)];   // W_edge
  if (t == 0){ np_s = 0; hasdup_s = 0; }

  const int K = min(cnt[r], CAP);

  if (K == 0){
    // all scores -10000 -> uniform attention over all nodes (lazy fallback; ~never taken)
    float* fb = pp;
    if (t < EMB) fb[t] = 0.f;
    __syncthreads();
    for (int idx=t; idx<NN*EMB; idx+=256) atomicAdd(&fb[idx&31], lrelu(nb[idx]));
    __syncthreads();
    if (t < 96) out[(size_t)r*96 + t] = fb[t&31] * (1.0f/NN);
    return;
  }

  for (int i=t; i<K; i+=256){
    const int d = bucketD[(size_t)r*CAP + i];
    ld[i]  = d;
    cdst[i] = d;                // speculative (valid if no dups)
    pay[i] = bucketF[(size_t)r*CAP + i];
    canon[i] = i;
  }
  __syncthreads();                                      // barrier 1

  // dedup sweep: atomicMin canon + dup flag in one pass
  for (int p=t; p<K*K; p+=256){
    const int i = p / K, j = p - i*K;
    if (j < i && ld[i] == ld[j]){ atomicMin(&canon[i], j); hasdup_s = 1; }
  }
  __syncthreads();                                      // barrier 2

  const bool dup = (hasdup_s != 0);                     // block-uniform
  int Kc = K;
  if (dup){
    // rare path (~28% of rows): compact slots + merge payload sums
    for (int i=t; i<K; i+=256){
      if (canon[i] == i){
        const int s2 = atomicAdd(&np_s, 1);
        slotidx[i] = s2;
        cdst[s2]   = ld[i];
      }
    }
    __syncthreads();
    Kc = np_s;
    for (int i=t; i<K; i+=256) slotof[i] = slotidx[canon[i]];
    for (int idx=t; idx<Kc*SES; idx+=256) sE[idx] = 0.f;
    __syncthreads();
  }

  // per-entry 64-dim edge embedding -> per-slot (sum); linear downstream so summing embs == summing eau/se
  for (int idx=t; idx<K*EMB; idx+=256){
    const int q = idx>>5, m = idx&31;
    const float4 p4 = pay[q];
    const float ea_ = lrelu(p4.x*sWea[2*m] + p4.y*sWea[2*m+1]);
    const float et_ = lrelu(p4.z*sWet[2*m] + p4.w*sWet[2*m+1]);
    if (!dup){
      sE[q*SES + m]      = ea_;
      sE[q*SES + 33 + m] = et_;
    } else {
      const int sl = slotof[q];
      atomicAdd(&sE[sl*SES + m],      ea_);
      atomicAdd(&sE[sl*SES + 33 + m], et_);
    }
  }
  __syncthreads();                                      // barrier 3

  // softmax: head h = wave h; lane q; shfl reductions
  if (t < 192){
    const int h = t >> 6, lane = t & 63;
    const float th = tar[r*4+h];
    float mx = -1e30f;
    for (int q0=0; q0<Kc; q0+=64){
      const int q = q0 + lane;
      if (q < Kc){
        float sev = 0.f;
        #pragma unroll
        for (int k=0;k<EMB;k++)
          sev += sWedge[h*64+k]*sE[q*SES+k] + sWedge[h*64+EMB+k]*sE[q*SES+33+k];
        const float s = lrelu(th + sev + nbr[cdst[q]*4+h]);
        pp[h*CAP+q] = s;
        mx = fmaxf(mx, s);
      }
    }
    #pragma unroll
    for (int d=32; d; d>>=1) mx = fmaxf(mx, __shfl_xor(mx, d, 64));
    float den = 0.f;
    for (int q0=0; q0<Kc; q0+=64){
      const int q = q0 + lane;
      if (q < Kc){
        const float p = __expf(pp[h*CAP+q] - mx);
        pp[h*CAP+q] = p;
        den += p;
      }
    }
    #pragma unroll
    for (int d=32; d; d>>=1) den += __shfl_xor(den, d, 64);
    if (lane == 0) hden[h] = den;
  }
  __syncthreads();                                      // barrier 4

  // output: 8 q-groups x 32 o-lanes; Wu_e row o streamed from global into regs (phase-local)
  {
    const int g = t >> 5, o = t & 31;
    const float4* wrow = (const float4*)(W_upd + (size_t)o*64);  // Wu_e row o = W_upd[o*64 + 0..31]
    const float4 w0=wrow[0], w1=wrow[1], w2=wrow[2], w3=wrow[3],
                 w4=wrow[4], w5=wrow[5], w6=wrow[6], w7=wrow[7];
    float a0=0.f, a1=0.f, a2=0.f;
    for (int q=g; q<Kc; q+=8){
      const float* se = &sE[q*SES];
      float ev;
      ev  = w0.x*se[0]  + w0.y*se[1]  + w0.z*se[2]  + w0.w*se[3];
      ev += w1.x*se[4]  + w1.y*se[5]  + w1.z*se[6]  + w1.w*se[7];
      ev += w2.x*se[8]  + w2.y*se[9]  + w2.z*se[10] + w2.w*se[11];
      ev += w3.x*se[12] + w3.y*se[13] + w3.z*se[14] + w3.w*se[15];
      ev += w4.x*se[16] + w4.y*se[17] + w4.z*se[18] + w4.w*se[19];
      ev += w5.x*se[20] + w5.y*se[21] + w5.z*se[22] + w5.w*se[23];
      ev += w6.x*se[24] + w6.y*se[25] + w6.z*se[26] + w6.w*se[27];
      ev += w7.x*se[28] + w7.y*se[29] + w7.z*se[30] + w7.w*se[31];
      const float u = lrelu(ev + nb[(size_t)cdst[q]*EMB + o]);
      a0 += pp[0*CAP+q]*u;
      a1 += pp[1*CAP+q]*u;
      a2 += pp[2*CAP+q]*u;
    }
    // pre-combine pairs (g, g+1) within the wave: g even <-> lane<32
    a0 += __shfl_down(a0, 32, 64);
    a1 += __shfl_down(a1, 32, 64);
    a2 += __shfl_down(a2, 32, 64);
    if ((g & 1) == 0){
      const int gg = g >> 1;
      partial[gg*96 +      o] = a0;
      partial[gg*96 + 32 + o] = a1;
      partial[gg*96 + 64 + o] = a2;
    }
  }
  __syncthreads();                                      // barrier 5
  if (t < 96){
    float s = 0.f;
    #pragma unroll
    for (int g=0; g<4; g++) s += partial[g*96 + t];
    out[(size_t)r*96 + t] = s / hden[t>>5];
  }
}

extern "C" void kernel_launch(void* const* d_in, const int* in_sizes, int n_in,
                              void* d_out, int out_size, void* d_ws, size_t ws_size,
                              hipStream_t stream)
{
  (void)in_sizes; (void)n_in; (void)out_size; (void)ws_size;
  const float* node_f    = (const float*)d_in[0];
  const float* edge_attr = (const float*)d_in[1];
  const float* edge_type = (const float*)d_in[2];
  const float* W_veh     = (const float*)d_in[3];
  const float* W_ped     = (const float*)d_in[4];
  const float* W_ea      = (const float*)d_in[5];
  const float* W_et      = (const float*)d_in[6];
  const float* W_att     = (const float*)d_in[7];
  const float* W_upd     = (const float*)d_in[8];
  const int*   ei        = (const int*)d_in[9];
  const unsigned char* veh_mask = (const unsigned char*)d_in[10];
  float* out = (float*)d_out;

  char* ws = (char*)d_ws;
  const size_t oCnt  = 0;                            // NN ints (zeroed: 6 KB)
  const size_t oBktF = oCnt  + (size_t)NN*4;         // NN*CAP float4 (6144 % 16 == 0)
  const size_t oBktD = oBktF + (size_t)NN*CAP*16;    // NN*CAP ints
  const size_t oTar  = oBktD + (size_t)NN*CAP*4;     // NN*4 floats
  const size_t oNbr  = oTar  + (size_t)NN*4*4;       // NN*4 floats
  const size_t oNb   = oNbr  + (size_t)NN*4*4;       // NN*32 floats

  int*    cnt     = (int*)   (ws + oCnt);
  float4* bucketF = (float4*)(ws + oBktF);
  int*    bucketD = (int*)   (ws + oBktD);
  float*  tar     = (float*) (ws + oTar);
  float*  nbr     = (float*) (ws + oNbr);
  float*  nb      = (float*) (ws + oNb);

  hipMemsetAsync(ws + oCnt, 0, (size_t)NN*4, stream);   // cnt = 0 (6 KB only)

  k_prep<<<EBLK + NBLK, 256, 0, stream>>>(node_f, edge_attr, edge_type,
                                          W_veh, W_ped, W_att, W_upd,
                                          ei, veh_mask, cnt, bucketD, bucketF,
                                          tar, nbr, nb);
  k_rows<<<NN, 256, 0, stream>>>(cnt, bucketD, bucketF, W_ea, W_et, W_att, W_upd,
                                 tar, nbr, nb, out);
}